// Round 1
// 81.621 us; speedup vs baseline: 1.0244x; 1.0244x over previous
//
#include <hip/hip_runtime.h>

// CrossCompress: B=16384, D=128, fp32.
// item_out[b,:]   = v * (e.w_vv) + e * (v.w_ev) + bias_v
// entity_out[b,:] = v * (e.w_ve) + e * (v.w_ee) + bias_e
//
// Layout: 32 lanes per row (float4 each => 128 floats = one row),
// 2 rows per wave64-half, and EACH THREAD processes two independent rows
// (row0 = 16*blk + 2*wave + half, row1 = row0 + 8). This doubles streaming
// bytes in flight per thread, overlaps the two shuffle-reduce chains, and
// amortizes the broadcast weight/bias loads across 2 rows.
// Block = 256 threads = 4 waves = 16 rows; grid = B/16 = 1024 blocks.

#define BROWS 16384
#define DDIM  128

__device__ __forceinline__ float dot4(const float4 a, const float4 b) {
    return a.x * b.x + a.y * b.y + a.z * b.z + a.w * b.w;
}

__global__ __launch_bounds__(256) void cross_compress_kernel(
    const float* __restrict__ v_in,    // item_embedding   [B,D]
    const float* __restrict__ e_in,    // entity_embedding [B,D]
    const float* __restrict__ w_vv,    // [D]
    const float* __restrict__ w_ve,
    const float* __restrict__ w_ev,
    const float* __restrict__ w_ee,
    const float* __restrict__ bias_v,
    const float* __restrict__ bias_e,
    float* __restrict__ out)           // [2,B,D] flat: item_out then entity_out
{
    const int lane = threadIdx.x & 63;
    const int wave = threadIdx.x >> 6;     // 0..3
    const int half = lane >> 5;            // row within this wave
    const int sub  = lane & 31;            // float4 slot within the row
    const int col  = sub * 4;

    const int row0 = blockIdx.x * 16 + wave * 2 + half;   // rows [16b, 16b+8)
    const int row1 = row0 + 8;                            // rows [16b+8, 16b+16)

    // Issue all four streaming loads before any dependent use (64 B in flight).
    const float4 v0 = *reinterpret_cast<const float4*>(v_in + row0 * DDIM + col);
    const float4 e0 = *reinterpret_cast<const float4*>(e_in + row0 * DDIM + col);
    const float4 v1 = *reinterpret_cast<const float4*>(v_in + row1 * DDIM + col);
    const float4 e1 = *reinterpret_cast<const float4*>(e_in + row1 * DDIM + col);

    // Broadcast weights/biases: L1-resident after first touch, loaded once
    // and reused for both rows.
    const float4 wvv = *reinterpret_cast<const float4*>(w_vv + col);
    const float4 wve = *reinterpret_cast<const float4*>(w_ve + col);
    const float4 wev = *reinterpret_cast<const float4*>(w_ev + col);
    const float4 wee = *reinterpret_cast<const float4*>(w_ee + col);
    const float4 bv  = *reinterpret_cast<const float4*>(bias_v + col);
    const float4 be  = *reinterpret_cast<const float4*>(bias_e + col);

    // Per-lane partial dot products, two independent rows.
    float a_vv = dot4(e0, wvv);   // e0 . w_vv
    float a_ev = dot4(v0, wev);   // v0 . w_ev
    float a_ve = dot4(e0, wve);   // e0 . w_ve
    float a_ee = dot4(v0, wee);   // v0 . w_ee
    float b_vv = dot4(e1, wvv);
    float b_ev = dot4(v1, wev);
    float b_ve = dot4(e1, wve);
    float b_ee = dot4(v1, wee);

    // Butterfly reduction within each 32-lane half (offsets <= 16 never cross
    // the half-wave boundary). Two independent chains overlap their
    // ds_bpermute latencies.
    #pragma unroll
    for (int off = 16; off >= 1; off >>= 1) {
        a_vv += __shfl_xor(a_vv, off, 64);
        a_ev += __shfl_xor(a_ev, off, 64);
        a_ve += __shfl_xor(a_ve, off, 64);
        a_ee += __shfl_xor(a_ee, off, 64);
        b_vv += __shfl_xor(b_vv, off, 64);
        b_ev += __shfl_xor(b_ev, off, 64);
        b_ve += __shfl_xor(b_ve, off, 64);
        b_ee += __shfl_xor(b_ee, off, 64);
    }

    float4 io0, eo0, io1, eo1;
    io0.x = v0.x * a_vv + e0.x * a_ev + bv.x;
    io0.y = v0.y * a_vv + e0.y * a_ev + bv.y;
    io0.z = v0.z * a_vv + e0.z * a_ev + bv.z;
    io0.w = v0.w * a_vv + e0.w * a_ev + bv.w;

    eo0.x = v0.x * a_ve + e0.x * a_ee + be.x;
    eo0.y = v0.y * a_ve + e0.y * a_ee + be.y;
    eo0.z = v0.z * a_ve + e0.z * a_ee + be.z;
    eo0.w = v0.w * a_ve + e0.w * a_ee + be.w;

    io1.x = v1.x * b_vv + e1.x * b_ev + bv.x;
    io1.y = v1.y * b_vv + e1.y * b_ev + bv.y;
    io1.z = v1.z * b_vv + e1.z * b_ev + bv.z;
    io1.w = v1.w * b_vv + e1.w * b_ev + bv.w;

    eo1.x = v1.x * b_ve + e1.x * b_ee + be.x;
    eo1.y = v1.y * b_ve + e1.y * b_ee + be.y;
    eo1.z = v1.z * b_ve + e1.z * b_ee + be.z;
    eo1.w = v1.w * b_ve + e1.w * b_ee + be.w;

    *reinterpret_cast<float4*>(out + (size_t)row0 * DDIM + col) = io0;
    *reinterpret_cast<float4*>(out + (size_t)BROWS * DDIM + (size_t)row0 * DDIM + col) = eo0;
    *reinterpret_cast<float4*>(out + (size_t)row1 * DDIM + col) = io1;
    *reinterpret_cast<float4*>(out + (size_t)BROWS * DDIM + (size_t)row1 * DDIM + col) = eo1;
}

extern "C" void kernel_launch(void* const* d_in, const int* in_sizes, int n_in,
                              void* d_out, int out_size, void* d_ws, size_t ws_size,
                              hipStream_t stream) {
    const float* v_in   = (const float*)d_in[0];
    const float* e_in   = (const float*)d_in[1];
    const float* w_vv   = (const float*)d_in[2];
    const float* w_ve   = (const float*)d_in[3];
    const float* w_ev   = (const float*)d_in[4];
    const float* w_ee   = (const float*)d_in[5];
    const float* bias_v = (const float*)d_in[6];
    const float* bias_e = (const float*)d_in[7];
    float* out = (float*)d_out;

    // 16 rows per 256-thread block
    const int grid = BROWS / 16;   // 1024
    cross_compress_kernel<<<grid, 256, 0, stream>>>(
        v_in, e_in, w_vv, w_ve, w_ev, w_ee, bias_v, bias_e, out);
}